// Round 1
// baseline (397.820 us; speedup 1.0000x reference)
//
#include <hip/hip_runtime.h>

#define DIMC 512
#define NTOK 4097
#define GH 64
#define GW 64
#define TH 16   // output rows per thread (7-slot accumulator ring)
#define WT 4    // output cols per thread (horizontal halo amortization)

// Fold w7 + padded(w5) + padded(w3) + identity into one 7x7 depthwise kernel,
// stored tap-major [t][c] so lanes (channels) read coalesced. Bias = b7+b5+b3.
__global__ __launch_bounds__(256) void prep_kernel(
    const float* __restrict__ w7, const float* __restrict__ b7,
    const float* __restrict__ w5, const float* __restrict__ b5,
    const float* __restrict__ w3, const float* __restrict__ b3,
    float* __restrict__ wc, float* __restrict__ bc)
{
    int idx = blockIdx.x * 256 + threadIdx.x;   // 0 .. 512*49-1
    if (idx < DIMC * 49) {
        int c = idx & (DIMC - 1);
        int t = idx >> 9;
        int dy = t / 7, dx = t - dy * 7;
        float v = w7[c * 49 + t];
        if (dy >= 1 && dy <= 5 && dx >= 1 && dx <= 5)
            v += w5[c * 25 + (dy - 1) * 5 + (dx - 1)];
        if (dy >= 2 && dy <= 4 && dx >= 2 && dx <= 4)
            v += w3[c * 9 + (dy - 2) * 3 + (dx - 2)];
        if (dy == 3 && dx == 3) v += 1.0f;      // identity (residual) term
        wc[t * DIMC + c] = v;
    }
    if (idx < DIMC) bc[idx] = b7[idx] + b5[idx] + b3[idx];
}

// cls token pass-through: out[b,0,:] = x[b,0,:]
__global__ __launch_bounds__(256) void cls_kernel(
    const float* __restrict__ x, float* __restrict__ out)
{
    int i = blockIdx.x * 256 + threadIdx.x;     // 0 .. 16*512-1
    int b = i >> 9, c = i & 511;
    size_t off = (size_t)b * NTOK * DIMC + c;
    out[off] = x[off];
}

// Depthwise combined 7x7 conv, channels on lanes, OUTPUT-STATIONARY streaming:
// each thread owns a TH x WT output tile for one channel. Input rows stream
// through a 10-wide register row; a ring of 7 accumulator rows x WT cols
// receives scattered contributions. Register budget: 49 wgt + 28 acc + 10 row
// (+addressing) ~= 110 — everything stays register-resident (vs the previous
// window formulation whose 49+49 arrays forced the compiler to re-load from
// cache inside the hot loop at VGPR_Count=68).
__global__ __launch_bounds__(256, 4) void dwconv_kernel(
    const float* __restrict__ x, const float* __restrict__ wc,
    const float* __restrict__ bc, float* __restrict__ out)
{
    const int lane  = threadIdx.x;                 // 0..63 (lane = channel)
    const int wtile = threadIdx.y;                 // 0..3 (wave-uniform)
    const int b     = blockIdx.z;                  // 0..15
    const int cg    = blockIdx.y >> 2;             // channel group 0..7
    const int h0    = (blockIdx.y & 3) * TH;       // output row base
    const int w0    = (blockIdx.x * 4 + wtile) * WT; // output col base (uniform/wave)
    const int cc    = (cg << 6) + lane;            // channel 0..511

    float wgt[49];
#pragma unroll
    for (int t = 0; t < 49; ++t) wgt[t] = wc[t * DIMC + cc];
    const float bias = bc[cc];

    const float* __restrict__ xin = x   + ((size_t)b * NTOK + 1) * DIMC + cc;
    float* __restrict__ op        = out + ((size_t)b * NTOK + 1) * DIMC + cc;

    float acc[7][WT];     // accumulator ring: slot k%7 holds output row h0+k
    float row[WT + 6];    // current input row, cols w0-3 .. w0+WT+2

#pragma unroll
    for (int i = 0; i < TH + 6; ++i) {             // input row r = h0-3+i
        const int r = h0 - 3 + i;

        // --- load one input row (10 coalesced 256B/wave loads) ---
        if (r >= 0 && r < GH) {                    // wave-uniform guard
            const float* __restrict__ rp = xin + (size_t)r * (GW * DIMC);
#pragma unroll
            for (int j = 0; j < WT + 6; ++j) {
                const int col = w0 - 3 + j;        // wave-uniform guard
                row[j] = (col >= 0 && col < GW) ? rp[(size_t)col * DIMC] : 0.0f;
            }
        } else {
#pragma unroll
            for (int j = 0; j < WT + 6; ++j) row[j] = 0.0f;
        }

        // --- scatter this row into the <=7 open output rows ---
        // output row k = i - dy uses weight row dy; all indices fold to
        // compile-time constants under the full unroll of i.
#pragma unroll
        for (int dy = 0; dy < 7; ++dy) {
            const int k = i - dy;
            if (k < 0 || k >= TH) continue;        // folds at compile time
            const int s = k % 7;
#pragma unroll
            for (int t = 0; t < WT; ++t) {
                float a = (dy == 0) ? bias : acc[s][t];
#pragma unroll
                for (int dx = 0; dx < 7; ++dx)
                    a = fmaf(wgt[dy * 7 + dx], row[t + dx], a);
                acc[s][t] = a;
            }
        }

        // --- output row k = i-6 just received its last contribution ---
        if (i >= 6) {
            const int k = i - 6;
            const int s = k % 7;
            const size_t ro = (size_t)(h0 + k) * GW;
#pragma unroll
            for (int t = 0; t < WT; ++t)
                op[(ro + (w0 + t)) * DIMC] = acc[s][t];
        }
    }
}

extern "C" void kernel_launch(void* const* d_in, const int* in_sizes, int n_in,
                              void* d_out, int out_size, void* d_ws, size_t ws_size,
                              hipStream_t stream)
{
    const float* x  = (const float*)d_in[0];
    const float* w7 = (const float*)d_in[1];
    const float* b7 = (const float*)d_in[2];
    const float* w5 = (const float*)d_in[3];
    const float* b5 = (const float*)d_in[4];
    const float* w3 = (const float*)d_in[5];
    const float* b3 = (const float*)d_in[6];
    float* out = (float*)d_out;
    float* wcomb = (float*)d_ws;            // 49*512 floats
    float* bcomb = wcomb + 49 * DIMC;       // 512 floats

    prep_kernel<<<98, 256, 0, stream>>>(w7, b7, w5, b5, w3, b3, wcomb, bcomb);
    cls_kernel<<<32, 256, 0, stream>>>(x, out);

    // 4 col-tiles/block x (8 cgroups x 4 row-tiles) x batch; block = 64 lanes x 4 waves
    dim3 grid(4, 32, 16);
    dim3 block(64, 4, 1);
    dwconv_kernel<<<grid, block, 0, stream>>>(x, wcomb, bcomb, out);
}

// Round 2
// 392.859 us; speedup vs baseline: 1.0126x; 1.0126x over previous
//
#include <hip/hip_runtime.h>

#define DIMC 512
#define NTOK 4097
#define GH 64
#define GW 64
#define TH 16   // output rows per thread (7-slot accumulator ring)
#define WT 4    // output cols per thread (horizontal halo amortization)

// Fold w7 + padded(w5) + padded(w3) + identity into one 7x7 depthwise kernel,
// stored tap-major [t][c] so lanes (channels) read coalesced. Bias = b7+b5+b3.
__global__ __launch_bounds__(256) void prep_kernel(
    const float* __restrict__ w7, const float* __restrict__ b7,
    const float* __restrict__ w5, const float* __restrict__ b5,
    const float* __restrict__ w3, const float* __restrict__ b3,
    float* __restrict__ wc, float* __restrict__ bc)
{
    int idx = blockIdx.x * 256 + threadIdx.x;   // 0 .. 512*49-1
    if (idx < DIMC * 49) {
        int c = idx & (DIMC - 1);
        int t = idx >> 9;
        int dy = t / 7, dx = t - dy * 7;
        float v = w7[c * 49 + t];
        if (dy >= 1 && dy <= 5 && dx >= 1 && dx <= 5)
            v += w5[c * 25 + (dy - 1) * 5 + (dx - 1)];
        if (dy >= 2 && dy <= 4 && dx >= 2 && dx <= 4)
            v += w3[c * 9 + (dy - 2) * 3 + (dx - 2)];
        if (dy == 3 && dx == 3) v += 1.0f;      // identity (residual) term
        wc[t * DIMC + c] = v;
    }
    if (idx < DIMC) bc[idx] = b7[idx] + b5[idx] + b3[idx];
}

// cls token pass-through: out[b,0,:] = x[b,0,:]
__global__ __launch_bounds__(256) void cls_kernel(
    const float* __restrict__ x, float* __restrict__ out)
{
    int i = blockIdx.x * 256 + threadIdx.x;     // 0 .. 16*512-1
    int b = i >> 9, c = i & 511;
    size_t off = (size_t)b * NTOK * DIMC + c;
    out[off] = x[off];
}

// Depthwise combined 7x7 conv, channels on lanes, output-stationary streaming.
// amdgpu_waves_per_eu(4,4): round-1 evidence showed the allocator chasing
// 8 waves/EU (VGPR=64) and spilling the acc ring to scratch (WRITE_SIZE
// 131->182 MB). Pinning min=max=4 waves/EU gives the full 128-VGPR budget
// and removes the incentive to shrink below it. Demand ~= 49 wgt + 28 acc
// + 10 row + addressing ~= 102 -> fits, zero spill.
__global__ __launch_bounds__(256)
__attribute__((amdgpu_waves_per_eu(4, 4)))
void dwconv_kernel(
    const float* __restrict__ x, const float* __restrict__ wc,
    const float* __restrict__ bc, float* __restrict__ out)
{
    const int lane  = threadIdx.x;                 // 0..63 (lane = channel)
    const int wtile = threadIdx.y;                 // 0..3 (wave-uniform)
    const int b     = blockIdx.z;                  // 0..15
    const int cg    = blockIdx.y >> 2;             // channel group 0..7
    const int h0    = (blockIdx.y & 3) * TH;       // output row base
    const int w0    = (blockIdx.x * 4 + wtile) * WT; // output col base (uniform/wave)
    const int cc    = (cg << 6) + lane;            // channel 0..511

    float wgt[49];
#pragma unroll
    for (int t = 0; t < 49; ++t) wgt[t] = wc[t * DIMC + cc];
    const float bias = bc[cc];

    const float* __restrict__ xin = x   + ((size_t)b * NTOK + 1) * DIMC + cc;
    float* __restrict__ op        = out + ((size_t)b * NTOK + 1) * DIMC + cc;

    float acc[7][WT];     // accumulator ring: slot k%7 holds output row h0+k
    float row[WT + 6];    // current input row, cols w0-3 .. w0+WT+2

#pragma unroll
    for (int i = 0; i < TH + 6; ++i) {             // input row r = h0-3+i
        const int r = h0 - 3 + i;

        // --- load one input row (10 coalesced 256B/wave loads) ---
        if (r >= 0 && r < GH) {                    // wave-uniform guard
            const float* __restrict__ rp = xin + (size_t)r * (GW * DIMC);
#pragma unroll
            for (int j = 0; j < WT + 6; ++j) {
                const int col = w0 - 3 + j;        // wave-uniform guard
                row[j] = (col >= 0 && col < GW) ? rp[(size_t)col * DIMC] : 0.0f;
            }
        } else {
#pragma unroll
            for (int j = 0; j < WT + 6; ++j) row[j] = 0.0f;
        }

        // --- scatter this row into the <=7 open output rows ---
        // output row k = i - dy uses weight row dy; all indices fold to
        // compile-time constants under the full unroll of i.
#pragma unroll
        for (int dy = 0; dy < 7; ++dy) {
            const int k = i - dy;
            if (k < 0 || k >= TH) continue;        // folds at compile time
            const int s = k % 7;
#pragma unroll
            for (int t = 0; t < WT; ++t) {
                float a = (dy == 0) ? bias : acc[s][t];
#pragma unroll
                for (int dx = 0; dx < 7; ++dx)
                    a = fmaf(wgt[dy * 7 + dx], row[t + dx], a);
                acc[s][t] = a;
            }
        }

        // --- output row k = i-6 just received its last contribution ---
        if (i >= 6) {
            const int k = i - 6;
            const int s = k % 7;
            const size_t ro = (size_t)(h0 + k) * GW;
#pragma unroll
            for (int t = 0; t < WT; ++t)
                op[(ro + (w0 + t)) * DIMC] = acc[s][t];
        }
    }
}

extern "C" void kernel_launch(void* const* d_in, const int* in_sizes, int n_in,
                              void* d_out, int out_size, void* d_ws, size_t ws_size,
                              hipStream_t stream)
{
    const float* x  = (const float*)d_in[0];
    const float* w7 = (const float*)d_in[1];
    const float* b7 = (const float*)d_in[2];
    const float* w5 = (const float*)d_in[3];
    const float* b5 = (const float*)d_in[4];
    const float* w3 = (const float*)d_in[5];
    const float* b3 = (const float*)d_in[6];
    float* out = (float*)d_out;
    float* wcomb = (float*)d_ws;            // 49*512 floats
    float* bcomb = wcomb + 49 * DIMC;       // 512 floats

    prep_kernel<<<98, 256, 0, stream>>>(w7, b7, w5, b5, w3, b3, wcomb, bcomb);
    cls_kernel<<<32, 256, 0, stream>>>(x, out);

    // 4 col-tiles/block x (8 cgroups x 4 row-tiles) x batch; block = 64 lanes x 4 waves
    dim3 grid(4, 32, 16);
    dim3 block(64, 4, 1);
    dwconv_kernel<<<grid, block, 0, stream>>>(x, wcomb, bcomb, out);
}